// Round 6
// baseline (564.837 us; speedup 1.0000x reference)
//
#include <hip/hip_runtime.h>

// Problem constants
#define H_HEADS 16
#define KV_HEADS 8
#define DHEAD 128
#define HID 2048
#define NQ 1024
#define SCACHE 8192
#define CPOS 4096
#define SEFF 5120

typedef __attribute__((ext_vector_type(8))) __bf16 bf16x8;
typedef __attribute__((ext_vector_type(4))) float f32x4;
typedef unsigned short u16;
typedef unsigned int u32;

__device__ __forceinline__ u16 f2b(float f) {  // f32 -> bf16 bits, RNE
  u32 u = __float_as_uint(f);
  u += 0x7fffu + ((u >> 16) & 1u);
  return (u16)(u >> 16);
}
__device__ __forceinline__ u16 f2b_t(float f) {  // truncating (for P only)
  return (u16)(__float_as_uint(f) >> 16);
}
__device__ __forceinline__ float b2f(u16 b) { return __uint_as_float(((u32)b) << 16); }
__device__ __forceinline__ u32 pk2(u16 a, u16 b) { return (u32)a | ((u32)b << 16); }
__device__ __forceinline__ uint2 f4b4(float4 v) {
  uint2 o;
  o.x = pk2(f2b(v.x), f2b(v.y));
  o.y = pk2(f2b(v.z), f2b(v.w));
  return o;
}

union U4 { uint4 v; u16 u[8]; };

// Wq|Wk|Wv f32 -> Wb bf16 (4096 x 2048 contiguous). 2,097,152 float4 chunks.
__global__ void __launch_bounds__(256) k_conv_w(const float* __restrict__ Wq,
                                                const float* __restrict__ Wk,
                                                const float* __restrict__ Wv,
                                                u16* __restrict__ Wb) {
  int i = blockIdx.x * 256 + threadIdx.x;
  const float* src;
  int off;
  if (i < 1048576) { src = Wq; off = i; }
  else if (i < 1572864) { src = Wk; off = i - 1048576; }
  else { src = Wv; off = i - 1572864; }
  float4 v = ((const float4*)src)[off];
  *(uint2*)(Wb + (size_t)i * 4) = f4b4(v);
}

// Generic f32 -> bf16 streaming convert (n4 float4 chunks) — used for Wo
__global__ void __launch_bounds__(256) k_f32_to_bf16(const float* __restrict__ src,
                                                     u16* __restrict__ dst, int n4) {
  int i = blockIdx.x * 256 + threadIdx.x;
  if (i < n4) {
    float4 v = ((const float4*)src)[i];
    *(uint2*)(dst + (size_t)i * 4) = f4b4(v);
  }
}

// hidden f32 (HID, NQ) -> hT bf16 (NQ, HID)
__global__ void __launch_bounds__(256) k_transpose_h(const float* __restrict__ hid,
                                                     u16* __restrict__ hT) {
  __shared__ __align__(16) float ls[64 * 68];
  int t = threadIdx.x;
  int c0 = blockIdx.x * 64, q0 = blockIdx.y * 64;
#pragma unroll
  for (int it = 0; it < 4; ++it) {
    int c = it * 256 + t;
    int row = c >> 4, ch = c & 15;
    *(float4*)(ls + row * 68 + ch * 4) =
        *(const float4*)(hid + (size_t)(c0 + row) * NQ + q0 + ch * 4);
  }
  __syncthreads();
  int ql = t & 63, cch = t >> 6;
  u32 ob[8];
#pragma unroll
  for (int j = 0; j < 8; ++j)
    ob[j] = pk2(f2b(ls[(cch * 16 + 2 * j) * 68 + ql]), f2b(ls[(cch * 16 + 2 * j + 1) * 68 + ql]));
  uint4* dst = (uint4*)(hT + (size_t)(q0 + ql) * HID + c0 + cch * 16);
  dst[0] = make_uint4(ob[0], ob[1], ob[2], ob[3]);
  dst[1] = make_uint4(ob[4], ob[5], ob[6], ob[7]);
}

// vcache f32 (kv, s<CPOS, d) -> vT bf16 (kv, d, s)
__global__ void __launch_bounds__(256) k_prep_vT(const float* __restrict__ vc,
                                                 u16* __restrict__ vT) {
  __shared__ __align__(16) float ls[64 * 132];
  int t = threadIdx.x;
  int s0 = blockIdx.x * 64;
  int kv = blockIdx.y;
#pragma unroll
  for (int it = 0; it < 8; ++it) {
    int c = it * 256 + t;
    int row = c >> 5, ch = c & 31;
    *(float4*)(ls + row * 132 + ch * 4) =
        *(const float4*)(vc + ((size_t)kv * SCACHE + s0 + row) * DHEAD + ch * 4);
  }
  __syncthreads();
  int d = t >> 1, sch = t & 1;
  u32 ob[16];
#pragma unroll
  for (int j = 0; j < 16; ++j)
    ob[j] = pk2(f2b(ls[(sch * 32 + 2 * j) * 132 + d]), f2b(ls[(sch * 32 + 2 * j + 1) * 132 + d]));
  uint4* dst = (uint4*)(vT + ((size_t)kv * DHEAD + d) * SEFF + s0 + sch * 32);
#pragma unroll
  for (int j = 0; j < 4; ++j)
    dst[j] = make_uint4(ob[4 * j], ob[4 * j + 1], ob[4 * j + 2], ob[4 * j + 3]);
}

// kcache f32 (kv, s<CPOS, d) -> kb bf16 (kv, s, d)
__global__ void __launch_bounds__(256) k_conv_k(const float* __restrict__ kc,
                                                u16* __restrict__ kb) {
  int i = blockIdx.x * 256 + threadIdx.x;  // 1,048,576 float4 chunks
  int kvi = i >> 17;
  int rem = i & 131071;
  float4 v = *(const float4*)(kc + (size_t)kvi * SCACHE * DHEAD + (size_t)rem * 4);
  *(uint2*)(kb + (size_t)kvi * SEFF * DHEAD + (size_t)rem * 4) = f4b4(v);
}

// qkv v-part rows (d-major) -> vT s in [CPOS, SEFF)
__global__ void __launch_bounds__(256) k_copy_vnew(const u16* __restrict__ qkv,
                                                   u16* __restrict__ vT) {
  int i = blockIdx.x * 256 + threadIdx.x;  // 131072 uint4 chunks
  int row = i >> 7, ch = i & 127;
  *(uint4*)(vT + (size_t)row * SEFF + CPOS + ch * 8) =
      *(const uint4*)(qkv + (size_t)(3072 + row) * NQ + ch * 8);
}

// Transposing RoPE: qkv q/k-parts (d-major) -> qb (h,q,d) [scaled] / kb rows CPOS+q.
// grid (24, 16): hh<16 -> q-head, else k-head kv=hh-16.
__global__ void __launch_bounds__(256) k_rope_t(const u16* __restrict__ qkv,
                                                const float* __restrict__ cosb,
                                                const float* __restrict__ sinb,
                                                u16* __restrict__ qb,
                                                u16* __restrict__ kb) {
  __shared__ __align__(16) u16 ls[64 * 136];  // [q][d]
  int t = threadIdx.x;
  int hh = blockIdx.x;
  int q0 = blockIdx.y * 64;
  bool isq = hh < 16;
  int rowbase = isq ? hh * DHEAD : HID + (hh - 16) * DHEAD;
#pragma unroll
  for (int it = 0; it < 4; ++it) {  // 128 d-rows x 64 q: 1024 uint4, scatter-transpose
    int c = it * 256 + t;
    int d = c >> 3, qc = (c & 7) * 8;
    U4 v;
    v.v = *(const uint4*)(qkv + (size_t)(rowbase + d) * NQ + q0 + qc);
#pragma unroll
    for (int e = 0; e < 8; ++e) ls[(qc + e) * 136 + d] = v.u[e];
  }
  __syncthreads();
  int ql = t & 63, hf = t >> 6;
  int q = q0 + ql;
  float scale = isq ? 0.08838834764831845f : 1.0f;
  u16* dst = isq ? (qb + ((size_t)hh * NQ + q) * DHEAD)
                 : (kb + ((size_t)(hh - 16) * SEFF + CPOS + q) * DHEAD);
#pragma unroll
  for (int g = 0; g < 4; ++g) {
    int d0 = hf * 32 + g * 8;
    U4 x, y;
    x.v = *(uint4*)(ls + ql * 136 + d0);
    y.v = *(uint4*)(ls + ql * 136 + (d0 ^ 64));
    float4 ca = *(const float4*)(cosb + (size_t)q * DHEAD + d0);
    float4 cb = *(const float4*)(cosb + (size_t)q * DHEAD + d0 + 4);
    float4 sa = *(const float4*)(sinb + (size_t)q * DHEAD + d0);
    float4 sb = *(const float4*)(sinb + (size_t)q * DHEAD + d0 + 4);
    float cs[8] = {ca.x, ca.y, ca.z, ca.w, cb.x, cb.y, cb.z, cb.w};
    float sn[8] = {sa.x, sa.y, sa.z, sa.w, sb.x, sb.y, sb.z, sb.w};
    float sgn = (d0 < 64) ? -1.0f : 1.0f;
    u32 ob[4];
#pragma unroll
    for (int e = 0; e < 4; ++e) {
      float r0 = (b2f(x.u[2 * e]) * cs[2 * e] + sgn * b2f(y.u[2 * e]) * sn[2 * e]) * scale;
      float r1 = (b2f(x.u[2 * e + 1]) * cs[2 * e + 1] + sgn * b2f(y.u[2 * e + 1]) * sn[2 * e + 1]) * scale;
      ob[e] = pk2(f2b(r0), f2b(r1));
    }
    *(uint4*)(dst + d0) = make_uint4(ob[0], ob[1], ob[2], ob[3]);
  }
}

// GEMM1: qkv(4096 x 1024) bf16 = Wb(4096 x 2048) bf16 @ hT^T + bias. Reg-prefetch pipeline.
__global__ void __launch_bounds__(256) k_gemm_qkv(
    const u16* __restrict__ Wb, const u16* __restrict__ hT, u16* __restrict__ qkv,
    const float* __restrict__ bq, const float* __restrict__ bk, const float* __restrict__ bv) {
  __shared__ __align__(16) u16 lsA[128 * 32];
  __shared__ __align__(16) u16 lsB[128 * 32];
  int t = threadIdx.x;
  int m0 = blockIdx.x * 128, n0 = blockIdx.y * 128;
  const u16* Abase = Wb + (size_t)m0 * HID;
  const u16* Bbase = hT + (size_t)n0 * HID;
  int lane = t & 63, wid = t >> 6;
  int quad = lane >> 4, l15 = lane & 15;
  int wr = wid >> 1, wc = wid & 1;
  int r0 = t >> 2, ch8 = (t & 3) * 8;
  uint4 ra[2], rb[2];
  ra[0] = *(const uint4*)(Abase + (size_t)r0 * HID + ch8);
  ra[1] = *(const uint4*)(Abase + (size_t)(64 + r0) * HID + ch8);
  rb[0] = *(const uint4*)(Bbase + (size_t)r0 * HID + ch8);
  rb[1] = *(const uint4*)(Bbase + (size_t)(64 + r0) * HID + ch8);
  f32x4 acc[4][4];
#pragma unroll
  for (int i = 0; i < 4; ++i)
#pragma unroll
    for (int j = 0; j < 4; ++j) acc[i][j] = (f32x4){0.f, 0.f, 0.f, 0.f};
  for (int kt = 0; kt < HID; kt += 32) {
    *(uint4*)(lsA + r0 * 32 + ch8) = ra[0];
    *(uint4*)(lsA + (64 + r0) * 32 + ch8) = ra[1];
    *(uint4*)(lsB + r0 * 32 + ch8) = rb[0];
    *(uint4*)(lsB + (64 + r0) * 32 + ch8) = rb[1];
    __syncthreads();
    int kn = kt + 32;
    if (kn < HID) {  // issue next-tile loads; waited at next iteration's LDS store
      ra[0] = *(const uint4*)(Abase + (size_t)r0 * HID + kn + ch8);
      ra[1] = *(const uint4*)(Abase + (size_t)(64 + r0) * HID + kn + ch8);
      rb[0] = *(const uint4*)(Bbase + (size_t)r0 * HID + kn + ch8);
      rb[1] = *(const uint4*)(Bbase + (size_t)(64 + r0) * HID + kn + ch8);
    }
    bf16x8 af[4], bfr[4];
#pragma unroll
    for (int i = 0; i < 4; ++i)
      af[i] = *(const bf16x8*)(lsA + (wr * 64 + i * 16 + l15) * 32 + quad * 8);
#pragma unroll
    for (int j = 0; j < 4; ++j)
      bfr[j] = *(const bf16x8*)(lsB + (wc * 64 + j * 16 + l15) * 32 + quad * 8);
#pragma unroll
    for (int i = 0; i < 4; ++i)
#pragma unroll
      for (int j = 0; j < 4; ++j)
        acc[i][j] = __builtin_amdgcn_mfma_f32_16x16x32_bf16(af[i], bfr[j], acc[i][j], 0, 0, 0);
    __syncthreads();
  }
#pragma unroll
  for (int i = 0; i < 4; ++i) {
#pragma unroll
    for (int r = 0; r < 4; ++r) {
      int m = m0 + wr * 64 + i * 16 + quad * 4 + r;
      float bias = (m < 2048) ? bq[m] : ((m < 3072) ? bk[m - 2048] : bv[m - 3072]);
#pragma unroll
      for (int j = 0; j < 4; ++j) {
        int n = n0 + wc * 64 + j * 16 + l15;
        qkv[(size_t)m * NQ + n] = f2b(acc[i][j][r] + bias);
      }
    }
  }
}

// Flash attention, S-split: grid (h, qt, z=4), 4 waves x 16 q-rows. Reg-prefetch K/V.
__global__ void __launch_bounds__(256) k_flash(const u16* __restrict__ qb,
                                               const u16* __restrict__ kb,
                                               const u16* __restrict__ vT,
                                               u16* __restrict__ po,
                                               float* __restrict__ pm,
                                               float* __restrict__ pl) {
  __shared__ __align__(16) u16 lsK[64 * 136];   // (s, d)
  __shared__ __align__(16) u16 lsV[144 * 68];   // (d, s); rows 128..143: ones/zeros
  __shared__ __align__(16) u16 lsP[4 * 16 * 68];
  int t = threadIdx.x;
  int h = blockIdx.x, qt = blockIdx.y, z = blockIdx.z;
  int kv = h >> 1;
  int q0 = qt * 64;
  int lane = t & 63, wid = t >> 6;
  int quad = lane >> 4, l15 = lane & 15;
  int qw = q0 + wid * 16;
  if (t < 128) {  // ones-row init (row 128 = 1.0, rows 129..143 = 0)
    int row = 128 + (t >> 3), ch = t & 7;
    u32 fill = (row == 128) ? 0x3f803f80u : 0u;
    *(uint4*)(lsV + row * 68 + ch * 8) = make_uint4(fill, fill, fill, fill);
  }
  // Q fragments: vectorized from qb (h, q, d)
  bf16x8 qf[4];
  const u16* qrow = qb + ((size_t)h * NQ + qw + l15) * DHEAD;
#pragma unroll
  for (int kc = 0; kc < 4; ++kc) qf[kc] = *(const bf16x8*)(qrow + kc * 32 + quad * 8);
  f32x4 oacc[9];
#pragma unroll
  for (int f = 0; f < 9; ++f) oacc[f] = (f32x4){0.f, 0.f, 0.f, 0.f};
  float m_run[4];
#pragma unroll
  for (int r = 0; r < 4; ++r) m_run[r] = -1e30f;
  u16* lsPw = lsP + wid * (16 * 68);
  int Svis = CPOS + q0 + 64;
  const u16* kbase = kb + (size_t)kv * SEFF * DHEAD;
  const u16* vbase = vT + (size_t)kv * DHEAD * SEFF;
  int kr = t >> 4, kc8 = (t & 15) * 8;
  int vr = t >> 3, vc8 = (t & 7) * 8;
  uint4 rk[4], rv[4];
#pragma unroll
  for (int it = 0; it < 4; ++it) {
    rk[it] = *(const uint4*)(kbase + (size_t)(z * 64 + it * 16 + kr) * DHEAD + kc8);
    rv[it] = *(const uint4*)(vbase + (size_t)(it * 32 + vr) * SEFF + z * 64 + vc8);
  }
  for (int s0 = z * 64; s0 < Svis; s0 += 256) {
#pragma unroll
    for (int it = 0; it < 4; ++it) {
      *(uint4*)(lsK + (it * 16 + kr) * 136 + kc8) = rk[it];
      *(uint4*)(lsV + (it * 32 + vr) * 68 + vc8) = rv[it];
    }
    __syncthreads();
    int sn = s0 + 256;
    if (sn < Svis) {  // prefetch next tile; waited at next LDS store
#pragma unroll
      for (int it = 0; it < 4; ++it) {
        rk[it] = *(const uint4*)(kbase + (size_t)(sn + it * 16 + kr) * DHEAD + kc8);
        rv[it] = *(const uint4*)(vbase + (size_t)(it * 32 + vr) * SEFF + sn + vc8);
      }
    }
    f32x4 sc[4];
#pragma unroll
    for (int js = 0; js < 4; ++js) {
      sc[js] = (f32x4){0.f, 0.f, 0.f, 0.f};
#pragma unroll
      for (int kc = 0; kc < 4; ++kc) {
        bf16x8 kf = *(const bf16x8*)(lsK + (js * 16 + l15) * 136 + kc * 32 + quad * 8);
        sc[js] = __builtin_amdgcn_mfma_f32_16x16x32_bf16(qf[kc], kf, sc[js], 0, 0, 0);
      }
    }
    if (s0 + 63 > CPOS + qw) {  // boundary tile: causal mask
#pragma unroll
      for (int r = 0; r < 4; ++r) {
        int lim = CPOS + qw + quad * 4 + r - s0;
#pragma unroll
        for (int js = 0; js < 4; ++js) {
          bool valid = (js * 16 + l15) <= lim;
          sc[js][r] = valid ? sc[js][r] : -1e30f;
        }
      }
    }
    float alpha[4];
#pragma unroll
    for (int r = 0; r < 4; ++r) {
      float mx = fmaxf(fmaxf(sc[0][r], sc[1][r]), fmaxf(sc[2][r], sc[3][r]));
      mx = fmaxf(mx, __shfl_xor(mx, 1, 64));
      mx = fmaxf(mx, __shfl_xor(mx, 2, 64));
      mx = fmaxf(mx, __shfl_xor(mx, 4, 64));
      mx = fmaxf(mx, __shfl_xor(mx, 8, 64));
      float mnew = fmaxf(m_run[r], mx);
      alpha[r] = __expf(m_run[r] - mnew);
      m_run[r] = mnew;
#pragma unroll
      for (int js = 0; js < 4; ++js) {
        float p = __expf(sc[js][r] - mnew);
        lsPw[(quad * 4 + r) * 68 + js * 16 + l15] = f2b_t(p);
      }
    }
#pragma unroll
    for (int f = 0; f < 9; ++f)
#pragma unroll
      for (int r = 0; r < 4; ++r) oacc[f][r] *= alpha[r];
    bf16x8 pf[2];
#pragma unroll
    for (int ks = 0; ks < 2; ++ks)
      pf[ks] = *(const bf16x8*)(lsPw + l15 * 68 + ks * 32 + quad * 8);
#pragma unroll
    for (int f = 0; f < 9; ++f) {
#pragma unroll
      for (int ks = 0; ks < 2; ++ks) {
        bf16x8 vf = *(const bf16x8*)(lsV + (f * 16 + l15) * 68 + ks * 32 + quad * 8);
        oacc[f] = __builtin_amdgcn_mfma_f32_16x16x32_bf16(pf[ks], vf, oacc[f], 0, 0, 0);
      }
    }
    __syncthreads();
  }
  int p = (h * 16 + qt) * 4 + z;
#pragma unroll
  for (int r = 0; r < 4; ++r) {
    int qloc = wid * 16 + quad * 4 + r;
    if (l15 == 0) {
      pm[(size_t)p * 64 + qloc] = m_run[r];
      pl[(size_t)p * 64 + qloc] = oacc[8][r];  // ones-row: running sum_s P
    }
#pragma unroll
    for (int f = 0; f < 8; ++f)
      po[(size_t)p * 8192 + qloc * 128 + f * 16 + l15] = f2b(oacc[f][r]);
  }
}

// Combine 4 S-split partials -> outT (NQ, H*D) bf16
__global__ void __launch_bounds__(256) k_combine(const u16* __restrict__ po,
                                                 const float* __restrict__ pm,
                                                 const float* __restrict__ pl,
                                                 u16* __restrict__ outT) {
  int t = threadIdx.x;
  int h = blockIdx.x, qt = blockIdx.y;
  int p = h * 16 + qt, q0 = qt * 64;
  int qloc = t >> 2, dq = (t & 3) * 32;
  float m0 = pm[(size_t)(p * 4 + 0) * 64 + qloc];
  float m1 = pm[(size_t)(p * 4 + 1) * 64 + qloc];
  float m2 = pm[(size_t)(p * 4 + 2) * 64 + qloc];
  float m3 = pm[(size_t)(p * 4 + 3) * 64 + qloc];
  float M = fmaxf(fmaxf(m0, m1), fmaxf(m2, m3));
  float w[4] = {__expf(m0 - M), __expf(m1 - M), __expf(m2 - M), __expf(m3 - M)};
  float L = 0.f;
#pragma unroll
  for (int zz = 0; zz < 4; ++zz) L += w[zz] * pl[(size_t)(p * 4 + zz) * 64 + qloc];
  float acc[32];
#pragma unroll
  for (int e = 0; e < 32; ++e) acc[e] = 0.f;
#pragma unroll
  for (int zz = 0; zz < 4; ++zz) {
    const u16* src = po + (size_t)(p * 4 + zz) * 8192 + qloc * 128 + dq;
#pragma unroll
    for (int j = 0; j < 4; ++j) {
      U4 v;
      v.v = *(const uint4*)(src + j * 8);
#pragma unroll
      for (int e = 0; e < 8; ++e) acc[j * 8 + e] += w[zz] * b2f(v.u[e]);
    }
  }
  float inv = 1.0f / L;
  u16* dst = outT + (size_t)(q0 + qloc) * HID + h * DHEAD + dq;
#pragma unroll
  for (int j = 0; j < 4; ++j) {
    u32 ob[4];
#pragma unroll
    for (int e = 0; e < 4; ++e)
      ob[e] = pk2(f2b(acc[j * 8 + 2 * e] * inv), f2b(acc[j * 8 + 2 * e + 1] * inv));
    *(uint4*)(dst + j * 8) = make_uint4(ob[0], ob[1], ob[2], ob[3]);
  }
}

// GEMM2: out(2048 x 1024) f32 = Wob bf16 @ attn; B^T = outT. 128m x 64n tiles, prefetch.
__global__ void __launch_bounds__(256) k_gemm_bt(const u16* __restrict__ A,
                                                 const u16* __restrict__ BT,
                                                 float* __restrict__ C) {
  __shared__ __align__(16) u16 lsA[128 * 32];
  __shared__ __align__(16) u16 lsB[64 * 32];
  int t = threadIdx.x;
  int m0 = blockIdx.x * 128, n0 = blockIdx.y * 64;
  const u16* Abase = A + (size_t)m0 * HID;
  const u16* Bbase = BT + (size_t)n0 * HID;
  int lane = t & 63, wid = t >> 6;
  int quad = lane >> 4, l15 = lane & 15;
  int wr = wid >> 1, wc = wid & 1;
  int r0 = t >> 2, ch8 = (t & 3) * 8;
  uint4 ra[2], rb;
  ra[0] = *(const uint4*)(Abase + (size_t)r0 * HID + ch8);
  ra[1] = *(const uint4*)(Abase + (size_t)(64 + r0) * HID + ch8);
  rb = *(const uint4*)(Bbase + (size_t)r0 * HID + ch8);
  f32x4 acc[4][2];
#pragma unroll
  for (int i = 0; i < 4; ++i)
#pragma unroll
    for (int j = 0; j < 2; ++j) acc[i][j] = (f32x4){0.f, 0.f, 0.f, 0.f};
  for (int kt = 0; kt < HID; kt += 32) {
    *(uint4*)(lsA + r0 * 32 + ch8) = ra[0];
    *(uint4*)(lsA + (64 + r0) * 32 + ch8) = ra[1];
    if (r0 < 64) *(uint4*)(lsB + r0 * 32 + ch8) = rb;
    __syncthreads();
    int kn = kt + 32;
    if (kn < HID) {
      ra[0] = *(const uint4*)(Abase + (size_t)r0 * HID + kn + ch8);
      ra[1] = *(const uint4*)(Abase + (size_t)(64 + r0) * HID + kn + ch8);
      rb = *(const uint4*)(Bbase + (size_t)r0 * HID + kn + ch8);
    }
    bf16x8 af[4], bfr[2];
#pragma unroll
    for (int i = 0; i < 4; ++i)
      af[i] = *(const bf16x8*)(lsA + (wr * 64 + i * 16 + l15) * 32 + quad * 8);
#pragma unroll
    for (int j = 0; j < 2; ++j)
      bfr[j] = *(const bf16x8*)(lsB + (wc * 32 + j * 16 + l15) * 32 + quad * 8);
#pragma unroll
    for (int i = 0; i < 4; ++i)
#pragma unroll
      for (int j = 0; j < 2; ++j)
        acc[i][j] = __builtin_amdgcn_mfma_f32_16x16x32_bf16(af[i], bfr[j], acc[i][j], 0, 0, 0);
    __syncthreads();
  }
#pragma unroll
  for (int i = 0; i < 4; ++i)
#pragma unroll
    for (int r = 0; r < 4; ++r) {
      int m = m0 + wr * 64 + i * 16 + quad * 4 + r;
#pragma unroll
      for (int j = 0; j < 2; ++j) {
        int n = n0 + wc * 32 + j * 16 + l15;
        C[(size_t)m * NQ + n] = acc[i][j][r];
      }
    }
}

extern "C" void kernel_launch(void* const* d_in, const int* in_sizes, int n_in,
                              void* d_out, int out_size, void* d_ws, size_t ws_size,
                              hipStream_t stream) {
  (void)in_sizes; (void)n_in; (void)out_size; (void)ws_size;
  const float* hidden = (const float*)d_in[0];
  const float* cosb = (const float*)d_in[1];
  const float* sinb = (const float*)d_in[2];
  const float* kcache = (const float*)d_in[6];
  const float* vcache = (const float*)d_in[7];
  const float* Wq = (const float*)d_in[8];
  const float* bq = (const float*)d_in[9];
  const float* Wk = (const float*)d_in[10];
  const float* bk = (const float*)d_in[11];
  const float* Wv = (const float*)d_in[12];
  const float* bv = (const float*)d_in[13];
  const float* Wo = (const float*)d_in[14];

  char* ws = (char*)d_ws;
  u16* qkv = (u16*)(ws);                    // [0 .. 8,388,608)
  u16* outT = (u16*)(ws + 8388608);         // [8,388,608 .. 12,582,912); hT overlays
  u16* hT = outT;
  u16* vT = (u16*)(ws + 12582912);          // [12,582,912 .. 23,068,672)
  u16* Wob = vT;                            // overlay: vT dead after flash
  u16* kb = (u16*)(ws + 23068672);          // [23,068,672 .. 33,554,432)
  u16* qb = (u16*)(ws + 33554432);          // [33,554,432 .. 37,748,736)
  u16* Wb = (u16*)(ws + 12582912);          // overlays vT+kb+qb; dead after gemm1
  u16* po = (u16*)(ws + 37748736);          // [37,748,736 .. 54,525,952)
  float* pm = (float*)(ws + 54525952);      // 256 KB
  float* pl = (float*)(ws + 54788096);      // 256 KB  (total ws 55,050,240)
  float* outb = (float*)d_out;

  k_conv_w<<<8192, 256, 0, stream>>>(Wq, Wk, Wv, Wb);
  k_transpose_h<<<dim3(32, 16), 256, 0, stream>>>(hidden, hT);
  k_gemm_qkv<<<dim3(32, 8), 256, 0, stream>>>(Wb, hT, qkv, bq, bk, bv);
  // Wb dead from here; its region becomes vT / kb / qb
  k_prep_vT<<<dim3(64, 8), 256, 0, stream>>>(vcache, vT);
  k_conv_k<<<4096, 256, 0, stream>>>(kcache, kb);
  k_rope_t<<<dim3(24, 16), 256, 0, stream>>>(qkv, cosb, sinb, qb, kb);
  k_copy_vnew<<<512, 256, 0, stream>>>(qkv, vT);
  k_flash<<<dim3(16, 16, 4), 256, 0, stream>>>(qb, kb, vT, po, pm, pl);
  k_combine<<<dim3(16, 16), 256, 0, stream>>>(po, pm, pl, outT);
  k_f32_to_bf16<<<4096, 256, 0, stream>>>(Wo, Wob, 1048576);  // overlay vT (dead)
  k_gemm_bt<<<dim3(16, 16), 256, 0, stream>>>(Wob, outT, outb);
}

// Round 7
// 388.139 us; speedup vs baseline: 1.4552x; 1.4552x over previous
//
#include <hip/hip_runtime.h>

// Problem constants
#define H_HEADS 16
#define KV_HEADS 8
#define DHEAD 128
#define HID 2048
#define NQ 1024
#define SCACHE 8192
#define CPOS 4096
#define SEFF 5120

typedef __attribute__((ext_vector_type(8))) __bf16 bf16x8;
typedef __attribute__((ext_vector_type(4))) float f32x4;
typedef unsigned short u16;
typedef unsigned int u32;

__device__ __forceinline__ u16 f2b(float f) {  // f32 -> bf16 bits, RNE
  u32 u = __float_as_uint(f);
  u += 0x7fffu + ((u >> 16) & 1u);
  return (u16)(u >> 16);
}
__device__ __forceinline__ u16 f2b_t(float f) {  // truncating (for P only)
  return (u16)(__float_as_uint(f) >> 16);
}
__device__ __forceinline__ float b2f(u16 b) { return __uint_as_float(((u32)b) << 16); }
__device__ __forceinline__ u32 pk2(u16 a, u16 b) { return (u32)a | ((u32)b << 16); }
__device__ __forceinline__ uint2 f4b4(float4 v) {
  uint2 o;
  o.x = pk2(f2b(v.x), f2b(v.y));
  o.y = pk2(f2b(v.z), f2b(v.w));
  return o;
}

union U4 { uint4 v; u16 u[8]; };

// Wq|Wk|Wv f32 -> Wb bf16 (4096 x 2048 contiguous). 2,097,152 float4 chunks.
__global__ void __launch_bounds__(256) k_conv_w(const float* __restrict__ Wq,
                                                const float* __restrict__ Wk,
                                                const float* __restrict__ Wv,
                                                u16* __restrict__ Wb) {
  int i = blockIdx.x * 256 + threadIdx.x;
  const float* src;
  int off;
  if (i < 1048576) { src = Wq; off = i; }
  else if (i < 1572864) { src = Wk; off = i - 1048576; }
  else { src = Wv; off = i - 1572864; }
  float4 v = ((const float4*)src)[off];
  *(uint2*)(Wb + (size_t)i * 4) = f4b4(v);
}

// Generic f32 -> bf16 streaming convert — used for Wo
__global__ void __launch_bounds__(256) k_f32_to_bf16(const float* __restrict__ src,
                                                     u16* __restrict__ dst, int n4) {
  int i = blockIdx.x * 256 + threadIdx.x;
  if (i < n4) {
    float4 v = ((const float4*)src)[i];
    *(uint2*)(dst + (size_t)i * 4) = f4b4(v);
  }
}

// hidden f32 (HID, NQ) -> hT bf16 (NQ, HID)
__global__ void __launch_bounds__(256) k_transpose_h(const float* __restrict__ hid,
                                                     u16* __restrict__ hT) {
  __shared__ __align__(16) float ls[64 * 68];
  int t = threadIdx.x;
  int c0 = blockIdx.x * 64, q0 = blockIdx.y * 64;
#pragma unroll
  for (int it = 0; it < 4; ++it) {
    int c = it * 256 + t;
    int row = c >> 4, ch = c & 15;
    *(float4*)(ls + row * 68 + ch * 4) =
        *(const float4*)(hid + (size_t)(c0 + row) * NQ + q0 + ch * 4);
  }
  __syncthreads();
  int ql = t & 63, cch = t >> 6;
  u32 ob[8];
#pragma unroll
  for (int j = 0; j < 8; ++j)
    ob[j] = pk2(f2b(ls[(cch * 16 + 2 * j) * 68 + ql]), f2b(ls[(cch * 16 + 2 * j + 1) * 68 + ql]));
  uint4* dst = (uint4*)(hT + (size_t)(q0 + ql) * HID + c0 + cch * 16);
  dst[0] = make_uint4(ob[0], ob[1], ob[2], ob[3]);
  dst[1] = make_uint4(ob[4], ob[5], ob[6], ob[7]);
}

// vcache f32 (kv, s<CPOS, d) -> vT bf16 (kv, d, s)
__global__ void __launch_bounds__(256) k_prep_vT(const float* __restrict__ vc,
                                                 u16* __restrict__ vT) {
  __shared__ __align__(16) float ls[64 * 132];
  int t = threadIdx.x;
  int s0 = blockIdx.x * 64;
  int kv = blockIdx.y;
#pragma unroll
  for (int it = 0; it < 8; ++it) {
    int c = it * 256 + t;
    int row = c >> 5, ch = c & 31;
    *(float4*)(ls + row * 132 + ch * 4) =
        *(const float4*)(vc + ((size_t)kv * SCACHE + s0 + row) * DHEAD + ch * 4);
  }
  __syncthreads();
  int d = t >> 1, sch = t & 1;
  u32 ob[16];
#pragma unroll
  for (int j = 0; j < 16; ++j)
    ob[j] = pk2(f2b(ls[(sch * 32 + 2 * j) * 132 + d]), f2b(ls[(sch * 32 + 2 * j + 1) * 132 + d]));
  uint4* dst = (uint4*)(vT + ((size_t)kv * DHEAD + d) * SEFF + s0 + sch * 32);
#pragma unroll
  for (int j = 0; j < 4; ++j)
    dst[j] = make_uint4(ob[4 * j], ob[4 * j + 1], ob[4 * j + 2], ob[4 * j + 3]);
}

// kcache f32 (kv, s<CPOS, d) -> kb bf16 (kv, s, d)
__global__ void __launch_bounds__(256) k_conv_k(const float* __restrict__ kc,
                                                u16* __restrict__ kb) {
  int i = blockIdx.x * 256 + threadIdx.x;  // 1,048,576 float4 chunks
  int kvi = i >> 17;
  int rem = i & 131071;
  float4 v = *(const float4*)(kc + (size_t)kvi * SCACHE * DHEAD + (size_t)rem * 4);
  *(uint2*)(kb + (size_t)kvi * SEFF * DHEAD + (size_t)rem * 4) = f4b4(v);
}

// qkv v-part rows (d-major) -> vT s in [CPOS, SEFF)
__global__ void __launch_bounds__(256) k_copy_vnew(const u16* __restrict__ qkv,
                                                   u16* __restrict__ vT) {
  int i = blockIdx.x * 256 + threadIdx.x;  // 131072 uint4 chunks
  int row = i >> 7, ch = i & 127;
  *(uint4*)(vT + (size_t)row * SEFF + CPOS + ch * 8) =
      *(const uint4*)(qkv + (size_t)(3072 + row) * NQ + ch * 8);
}

// Transposing RoPE: qkv q/k-parts (d-major) -> qb (h,q,d) [scaled] / kb rows CPOS+q.
__global__ void __launch_bounds__(256) k_rope_t(const u16* __restrict__ qkv,
                                                const float* __restrict__ cosb,
                                                const float* __restrict__ sinb,
                                                u16* __restrict__ qb,
                                                u16* __restrict__ kb) {
  __shared__ __align__(16) u16 ls[64 * 136];  // [q][d]
  int t = threadIdx.x;
  int hh = blockIdx.x;
  int q0 = blockIdx.y * 64;
  bool isq = hh < 16;
  int rowbase = isq ? hh * DHEAD : HID + (hh - 16) * DHEAD;
#pragma unroll
  for (int it = 0; it < 4; ++it) {
    int c = it * 256 + t;
    int d = c >> 3, qc = (c & 7) * 8;
    U4 v;
    v.v = *(const uint4*)(qkv + (size_t)(rowbase + d) * NQ + q0 + qc);
#pragma unroll
    for (int e = 0; e < 8; ++e) ls[(qc + e) * 136 + d] = v.u[e];
  }
  __syncthreads();
  int ql = t & 63, hf = t >> 6;
  int q = q0 + ql;
  float scale = isq ? 0.08838834764831845f : 1.0f;
  u16* dst = isq ? (qb + ((size_t)hh * NQ + q) * DHEAD)
                 : (kb + ((size_t)(hh - 16) * SEFF + CPOS + q) * DHEAD);
#pragma unroll
  for (int g = 0; g < 4; ++g) {
    int d0 = hf * 32 + g * 8;
    U4 x, y;
    x.v = *(uint4*)(ls + ql * 136 + d0);
    y.v = *(uint4*)(ls + ql * 136 + (d0 ^ 64));
    float4 ca = *(const float4*)(cosb + (size_t)q * DHEAD + d0);
    float4 cb = *(const float4*)(cosb + (size_t)q * DHEAD + d0 + 4);
    float4 sa = *(const float4*)(sinb + (size_t)q * DHEAD + d0);
    float4 sb = *(const float4*)(sinb + (size_t)q * DHEAD + d0 + 4);
    float cs[8] = {ca.x, ca.y, ca.z, ca.w, cb.x, cb.y, cb.z, cb.w};
    float sn[8] = {sa.x, sa.y, sa.z, sa.w, sb.x, sb.y, sb.z, sb.w};
    float sgn = (d0 < 64) ? -1.0f : 1.0f;
    u32 ob[4];
#pragma unroll
    for (int e = 0; e < 4; ++e) {
      float r0 = (b2f(x.u[2 * e]) * cs[2 * e] + sgn * b2f(y.u[2 * e]) * sn[2 * e]) * scale;
      float r1 = (b2f(x.u[2 * e + 1]) * cs[2 * e + 1] + sgn * b2f(y.u[2 * e + 1]) * sn[2 * e + 1]) * scale;
      ob[e] = pk2(f2b(r0), f2b(r1));
    }
    *(uint4*)(dst + d0) = make_uint4(ob[0], ob[1], ob[2], ob[3]);
  }
}

// GEMM1 (round-5 double-barrier shape): qkv = Wb @ hT^T + bias
__global__ void __launch_bounds__(256) k_gemm_qkv(
    const u16* __restrict__ Wb, const u16* __restrict__ hT, u16* __restrict__ qkv,
    const float* __restrict__ bq, const float* __restrict__ bk, const float* __restrict__ bv) {
  __shared__ __align__(16) u16 lsA[128 * 32];
  __shared__ __align__(16) u16 lsB[128 * 32];
  int t = threadIdx.x;
  int m0 = blockIdx.x * 128, n0 = blockIdx.y * 128;
  const u16* Abase = Wb + (size_t)m0 * HID;
  int lane = t & 63, wid = t >> 6;
  int quad = lane >> 4, l15 = lane & 15;
  int wr = wid >> 1, wc = wid & 1;
  f32x4 acc[4][4];
#pragma unroll
  for (int i = 0; i < 4; ++i)
#pragma unroll
    for (int j = 0; j < 4; ++j) acc[i][j] = (f32x4){0.f, 0.f, 0.f, 0.f};
  for (int kt = 0; kt < HID; kt += 32) {
    __syncthreads();
#pragma unroll
    for (int it = 0; it < 2; ++it) {
      int c = it * 256 + t;
      int row = c >> 2, ch = c & 3;
      *(uint4*)(lsA + row * 32 + ch * 8) =
          *(const uint4*)(Abase + (size_t)row * HID + kt + ch * 8);
      *(uint4*)(lsB + row * 32 + ch * 8) =
          *(const uint4*)(hT + (size_t)(n0 + row) * HID + kt + ch * 8);
    }
    __syncthreads();
    bf16x8 af[4], bfr[4];
#pragma unroll
    for (int i = 0; i < 4; ++i)
      af[i] = *(const bf16x8*)(lsA + (wr * 64 + i * 16 + l15) * 32 + quad * 8);
#pragma unroll
    for (int j = 0; j < 4; ++j)
      bfr[j] = *(const bf16x8*)(lsB + (wc * 64 + j * 16 + l15) * 32 + quad * 8);
#pragma unroll
    for (int i = 0; i < 4; ++i)
#pragma unroll
      for (int j = 0; j < 4; ++j)
        acc[i][j] = __builtin_amdgcn_mfma_f32_16x16x32_bf16(af[i], bfr[j], acc[i][j], 0, 0, 0);
  }
#pragma unroll
  for (int i = 0; i < 4; ++i) {
#pragma unroll
    for (int r = 0; r < 4; ++r) {
      int m = m0 + wr * 64 + i * 16 + quad * 4 + r;
      float bias = (m < 2048) ? bq[m] : ((m < 3072) ? bk[m - 2048] : bv[m - 3072]);
#pragma unroll
      for (int j = 0; j < 4; ++j) {
        int n = n0 + wc * 64 + j * 16 + l15;
        qkv[(size_t)m * NQ + n] = f2b(acc[i][j][r] + bias);
      }
    }
  }
}

// Flash attention: grid (h, qt8, z=4), 512 threads (8 waves x 16 q-rows = 128 q/block).
// Round-5 double-barrier staging (no reg prefetch — avoids scratch spill).
__global__ void __launch_bounds__(512) k_flash(const u16* __restrict__ qb,
                                               const u16* __restrict__ kb,
                                               const u16* __restrict__ vT,
                                               u16* __restrict__ po,
                                               float* __restrict__ pm,
                                               float* __restrict__ pl) {
  __shared__ __align__(16) u16 lsK[64 * 136];   // (s, d)
  __shared__ __align__(16) u16 lsV[144 * 68];   // (d, s); rows 128..143: ones/zeros
  __shared__ __align__(16) u16 lsP[8 * 16 * 68];
  int t = threadIdx.x;
  int h = blockIdx.x, qt = blockIdx.y, z = blockIdx.z;
  int kv = h >> 1;
  int q0 = qt * 128;
  int lane = t & 63, wid = t >> 6;
  int quad = lane >> 4, l15 = lane & 15;
  int qw = q0 + wid * 16;
  if (t < 128) {  // ones-row init (row 128 = 1.0, rows 129..143 = 0)
    int row = 128 + (t >> 3), ch = t & 7;
    u32 fill = (row == 128) ? 0x3f803f80u : 0u;
    *(uint4*)(lsV + row * 68 + ch * 8) = make_uint4(fill, fill, fill, fill);
  }
  bf16x8 qf[4];
  const u16* qrow = qb + ((size_t)h * NQ + qw + l15) * DHEAD;
#pragma unroll
  for (int kc = 0; kc < 4; ++kc) qf[kc] = *(const bf16x8*)(qrow + kc * 32 + quad * 8);
  f32x4 oacc[9];
#pragma unroll
  for (int f = 0; f < 9; ++f) oacc[f] = (f32x4){0.f, 0.f, 0.f, 0.f};
  float m_run[4];
#pragma unroll
  for (int r = 0; r < 4; ++r) m_run[r] = -1e30f;
  u16* lsPw = lsP + wid * (16 * 68);
  int Svis = CPOS + q0 + 128;
  const u16* kbase = kb + (size_t)kv * SEFF * DHEAD;
  const u16* vbase = vT + (size_t)kv * DHEAD * SEFF;
  for (int s0 = z * 64; s0 < Svis; s0 += 256) {
#pragma unroll
    for (int it = 0; it < 2; ++it) {  // K: 1024 chunks; V: 1024 chunks; 512 threads
      int c = it * 512 + t;
      int rowK = c >> 4, chK = c & 15;
      *(uint4*)(lsK + rowK * 136 + chK * 8) =
          *(const uint4*)(kbase + (size_t)(s0 + rowK) * DHEAD + chK * 8);
      int rowV = c >> 3, chV = c & 7;
      *(uint4*)(lsV + rowV * 68 + chV * 8) =
          *(const uint4*)(vbase + (size_t)rowV * SEFF + s0 + chV * 8);
    }
    __syncthreads();
    f32x4 sc[4];
#pragma unroll
    for (int js = 0; js < 4; ++js) {
      sc[js] = (f32x4){0.f, 0.f, 0.f, 0.f};
#pragma unroll
      for (int kc = 0; kc < 4; ++kc) {
        bf16x8 kf = *(const bf16x8*)(lsK + (js * 16 + l15) * 136 + kc * 32 + quad * 8);
        sc[js] = __builtin_amdgcn_mfma_f32_16x16x32_bf16(qf[kc], kf, sc[js], 0, 0, 0);
      }
    }
    if (s0 + 63 > CPOS + qw) {  // boundary tile for this wave: causal mask
#pragma unroll
      for (int r = 0; r < 4; ++r) {
        int lim = CPOS + qw + quad * 4 + r - s0;
#pragma unroll
        for (int js = 0; js < 4; ++js) {
          bool valid = (js * 16 + l15) <= lim;
          sc[js][r] = valid ? sc[js][r] : -1e30f;
        }
      }
    }
    float alpha[4];
#pragma unroll
    for (int r = 0; r < 4; ++r) {
      float mx = fmaxf(fmaxf(sc[0][r], sc[1][r]), fmaxf(sc[2][r], sc[3][r]));
      mx = fmaxf(mx, __shfl_xor(mx, 1, 64));
      mx = fmaxf(mx, __shfl_xor(mx, 2, 64));
      mx = fmaxf(mx, __shfl_xor(mx, 4, 64));
      mx = fmaxf(mx, __shfl_xor(mx, 8, 64));
      float mnew = fmaxf(m_run[r], mx);
      alpha[r] = __expf(m_run[r] - mnew);
      m_run[r] = mnew;
#pragma unroll
      for (int js = 0; js < 4; ++js) {
        float p = __expf(sc[js][r] - mnew);
        lsPw[(quad * 4 + r) * 68 + js * 16 + l15] = f2b_t(p);
      }
    }
#pragma unroll
    for (int f = 0; f < 9; ++f)
#pragma unroll
      for (int r = 0; r < 4; ++r) oacc[f][r] *= alpha[r];
    bf16x8 pf[2];
#pragma unroll
    for (int ks = 0; ks < 2; ++ks)
      pf[ks] = *(const bf16x8*)(lsPw + l15 * 68 + ks * 32 + quad * 8);
#pragma unroll
    for (int f = 0; f < 9; ++f) {
#pragma unroll
      for (int ks = 0; ks < 2; ++ks) {
        bf16x8 vf = *(const bf16x8*)(lsV + (f * 16 + l15) * 68 + ks * 32 + quad * 8);
        oacc[f] = __builtin_amdgcn_mfma_f32_16x16x32_bf16(pf[ks], vf, oacc[f], 0, 0, 0);
      }
    }
    __syncthreads();
  }
  int p = (h * 8 + qt) * 4 + z;
#pragma unroll
  for (int r = 0; r < 4; ++r) {
    int qloc = wid * 16 + quad * 4 + r;  // 0..127
    if (l15 == 0) {
      pm[(size_t)p * 128 + qloc] = m_run[r];
      pl[(size_t)p * 128 + qloc] = oacc[8][r];  // ones-row: running sum_s P
    }
#pragma unroll
    for (int f = 0; f < 8; ++f)
      po[(size_t)p * 16384 + qloc * 128 + f * 16 + l15] = f2b(oacc[f][r]);
  }
}

// Combine 4 S-split partials -> outT (NQ, H*D) bf16
__global__ void __launch_bounds__(256) k_combine(const u16* __restrict__ po,
                                                 const float* __restrict__ pm,
                                                 const float* __restrict__ pl,
                                                 u16* __restrict__ outT) {
  int t = threadIdx.x;
  int h = blockIdx.x, qt = blockIdx.y;
  int q = qt * 64 + (t >> 2);  // 0..1023
  int dq = (t & 3) * 32;
  int pb = (h * 8 + (q >> 7)) * 4;
  int ql = q & 127;
  float m0 = pm[(size_t)(pb + 0) * 128 + ql];
  float m1 = pm[(size_t)(pb + 1) * 128 + ql];
  float m2 = pm[(size_t)(pb + 2) * 128 + ql];
  float m3 = pm[(size_t)(pb + 3) * 128 + ql];
  float M = fmaxf(fmaxf(m0, m1), fmaxf(m2, m3));
  float w[4] = {__expf(m0 - M), __expf(m1 - M), __expf(m2 - M), __expf(m3 - M)};
  float L = 0.f;
#pragma unroll
  for (int zz = 0; zz < 4; ++zz) L += w[zz] * pl[(size_t)(pb + zz) * 128 + ql];
  float acc[32];
#pragma unroll
  for (int e = 0; e < 32; ++e) acc[e] = 0.f;
#pragma unroll
  for (int zz = 0; zz < 4; ++zz) {
    const u16* src = po + (size_t)(pb + zz) * 16384 + ql * 128 + dq;
#pragma unroll
    for (int j = 0; j < 4; ++j) {
      U4 v;
      v.v = *(const uint4*)(src + j * 8);
#pragma unroll
      for (int e = 0; e < 8; ++e) acc[j * 8 + e] += w[zz] * b2f(v.u[e]);
    }
  }
  float inv = 1.0f / L;
  u16* dst = outT + (size_t)q * HID + h * DHEAD + dq;
#pragma unroll
  for (int j = 0; j < 4; ++j) {
    u32 ob[4];
#pragma unroll
    for (int e = 0; e < 4; ++e)
      ob[e] = pk2(f2b(acc[j * 8 + 2 * e] * inv), f2b(acc[j * 8 + 2 * e + 1] * inv));
    *(uint4*)(dst + j * 8) = make_uint4(ob[0], ob[1], ob[2], ob[3]);
  }
}

// GEMM2: out f32 = Wob bf16 @ attn; B^T = outT. 128m x 64n tiles, 256 blocks, double-barrier.
__global__ void __launch_bounds__(256) k_gemm_bt(const u16* __restrict__ A,
                                                 const u16* __restrict__ BT,
                                                 float* __restrict__ C) {
  __shared__ __align__(16) u16 lsA[128 * 32];
  __shared__ __align__(16) u16 lsB[64 * 32];
  int t = threadIdx.x;
  int m0 = blockIdx.x * 128, n0 = blockIdx.y * 64;
  const u16* Abase = A + (size_t)m0 * HID;
  const u16* Bbase = BT + (size_t)n0 * HID;
  int lane = t & 63, wid = t >> 6;
  int quad = lane >> 4, l15 = lane & 15;
  int wr = wid >> 1, wc = wid & 1;
  f32x4 acc[4][2];
#pragma unroll
  for (int i = 0; i < 4; ++i)
#pragma unroll
    for (int j = 0; j < 2; ++j) acc[i][j] = (f32x4){0.f, 0.f, 0.f, 0.f};
  for (int kt = 0; kt < HID; kt += 32) {
    __syncthreads();
#pragma unroll
    for (int it = 0; it < 2; ++it) {  // A: 512 chunks
      int c = it * 256 + t;
      int row = c >> 2, ch = c & 3;
      *(uint4*)(lsA + row * 32 + ch * 8) =
          *(const uint4*)(Abase + (size_t)row * HID + kt + ch * 8);
    }
    {  // B: 256 chunks
      int row = t >> 2, ch = t & 3;
      *(uint4*)(lsB + row * 32 + ch * 8) =
          *(const uint4*)(Bbase + (size_t)row * HID + kt + ch * 8);
    }
    __syncthreads();
    bf16x8 af[4], bfr[2];
#pragma unroll
    for (int i = 0; i < 4; ++i)
      af[i] = *(const bf16x8*)(lsA + (wr * 64 + i * 16 + l15) * 32 + quad * 8);
#pragma unroll
    for (int j = 0; j < 2; ++j)
      bfr[j] = *(const bf16x8*)(lsB + (wc * 32 + j * 16 + l15) * 32 + quad * 8);
#pragma unroll
    for (int i = 0; i < 4; ++i)
#pragma unroll
      for (int j = 0; j < 2; ++j)
        acc[i][j] = __builtin_amdgcn_mfma_f32_16x16x32_bf16(af[i], bfr[j], acc[i][j], 0, 0, 0);
  }
#pragma unroll
  for (int i = 0; i < 4; ++i)
#pragma unroll
    for (int r = 0; r < 4; ++r) {
      int m = m0 + wr * 64 + i * 16 + quad * 4 + r;
#pragma unroll
      for (int j = 0; j < 2; ++j) {
        int n = n0 + wc * 32 + j * 16 + l15;
        C[(size_t)m * NQ + n] = acc[i][j][r];
      }
    }
}

extern "C" void kernel_launch(void* const* d_in, const int* in_sizes, int n_in,
                              void* d_out, int out_size, void* d_ws, size_t ws_size,
                              hipStream_t stream) {
  (void)in_sizes; (void)n_in; (void)out_size; (void)ws_size;
  const float* hidden = (const float*)d_in[0];
  const float* cosb = (const float*)d_in[1];
  const float* sinb = (const float*)d_in[2];
  const float* kcache = (const float*)d_in[6];
  const float* vcache = (const float*)d_in[7];
  const float* Wq = (const float*)d_in[8];
  const float* bq = (const float*)d_in[9];
  const float* Wk = (const float*)d_in[10];
  const float* bk = (const float*)d_in[11];
  const float* Wv = (const float*)d_in[12];
  const float* bv = (const float*)d_in[13];
  const float* Wo = (const float*)d_in[14];

  char* ws = (char*)d_ws;
  u16* qkv = (u16*)(ws);                    // [0 .. 8,388,608)
  u16* outT = (u16*)(ws + 8388608);         // [8,388,608 .. 12,582,912); hT overlays
  u16* hT = outT;
  u16* vT = (u16*)(ws + 12582912);          // [12,582,912 .. 23,068,672)
  u16* Wob = vT;                            // overlay: vT dead after flash
  u16* kb = (u16*)(ws + 23068672);          // [23,068,672 .. 33,554,432)
  u16* qb = (u16*)(ws + 33554432);          // [33,554,432 .. 37,748,736)
  u16* Wb = (u16*)(ws + 12582912);          // overlays vT+kb; dead after gemm1
  u16* po = (u16*)(ws + 37748736);          // [37,748,736 .. 54,525,952)
  float* pm = (float*)(ws + 54525952);      // 256 KB
  float* pl = (float*)(ws + 54788096);      // 256 KB  (total ws 55,050,240)
  float* outb = (float*)d_out;

  k_conv_w<<<8192, 256, 0, stream>>>(Wq, Wk, Wv, Wb);
  k_transpose_h<<<dim3(32, 16), 256, 0, stream>>>(hidden, hT);
  k_gemm_qkv<<<dim3(32, 8), 256, 0, stream>>>(Wb, hT, qkv, bq, bk, bv);
  // Wb dead from here; its region becomes vT / kb
  k_prep_vT<<<dim3(64, 8), 256, 0, stream>>>(vcache, vT);
  k_conv_k<<<4096, 256, 0, stream>>>(kcache, kb);
  k_rope_t<<<dim3(24, 16), 256, 0, stream>>>(qkv, cosb, sinb, qb, kb);
  k_copy_vnew<<<512, 256, 0, stream>>>(qkv, vT);
  k_flash<<<dim3(16, 8, 4), 512, 0, stream>>>(qb, kb, vT, po, pm, pl);
  k_f32_to_bf16<<<4096, 256, 0, stream>>>(Wo, Wob, 1048576);  // overlay vT (dead)
  k_combine<<<dim3(16, 16), 256, 0, stream>>>(po, pm, pl, outT);
  k_gemm_bt<<<dim3(16, 16), 256, 0, stream>>>(Wob, outT, outb);
}